// Round 9
// baseline (249.242 us; speedup 1.0000x reference)
//
#include <hip/hip_runtime.h>
#include <hip/hip_bf16.h>

typedef __hip_bfloat16 bf16;
typedef __attribute__((ext_vector_type(8))) short bf16x8;   // 8 bf16 = 4 VGPRs
typedef __attribute__((ext_vector_type(4))) float f32x4;

constexpr int Bc  = 2;
constexpr int Sc  = 2048;
constexpr int Dc  = 1024;
constexpr int Hc  = 16;
constexpr int DHc = 64;
constexpr int BS  = Bc * Sc;   // 4096 rows
constexpr int NT  = Sc / 64;   // 32 key tiles

__device__ __forceinline__ float bs2f(unsigned short u) {
    union { unsigned int i; float f; } v; v.i = ((unsigned int)u) << 16; return v.f;
}
__device__ __forceinline__ short f2bs(float x) {
    bf16 h = __float2bfloat16(x);
    return *reinterpret_cast<short*>(&h);
}

// async global->LDS, 16B per lane. LDS dest is wave-uniform base + lane*16.
typedef const __attribute__((address_space(1))) unsigned int* as1_u32p;
typedef __attribute__((address_space(3))) unsigned int* as3_u32p;
__device__ __forceinline__ void gl_lds16(const void* g, void* l) {
    __builtin_amdgcn_global_load_lds((as1_u32p)g, (as3_u32p)l, 16, 0, 0);
}

// ---------------------------------------------------------------------------
// cast x (f32) -> bf16, same layout
// ---------------------------------------------------------------------------
__global__ __launch_bounds__(256) void cast_x(const float* __restrict__ in,
                                              short* __restrict__ out) {
    const int i = (blockIdx.x * 256 + threadIdx.x) * 4;
    const float4 v = *(const float4*)(in + i);
    ushort4 o;
    o.x = (unsigned short)f2bs(v.x);
    o.y = (unsigned short)f2bs(v.y);
    o.z = (unsigned short)f2bs(v.z);
    o.w = (unsigned short)f2bs(v.w);
    *(ushort4*)(out + i) = o;
}

// ---------------------------------------------------------------------------
// transpose + cast: in f32 [1024 k][1024 n] -> out bf16 [n][k].  z picks W.
// ---------------------------------------------------------------------------
__global__ __launch_bounds__(256) void transpose_cast(
    const float* __restrict__ w0, const float* __restrict__ w1,
    const float* __restrict__ w2, const float* __restrict__ w3,
    short* __restrict__ outbase)
{
    __shared__ float T[64][65];
    const int z = blockIdx.z;
    const float* in = (z == 0) ? w0 : (z == 1) ? w1 : (z == 2) ? w2 : w3;
    short* out = outbase + (size_t)z * 1024 * 1024;
    const int k0 = blockIdx.x * 64, n0 = blockIdx.y * 64;
    const int t = threadIdx.x;
    #pragma unroll
    for (int it = 0; it < 4; ++it) {
        const int s = it * 256 + t;
        const int r = s >> 4, c = (s & 15) * 4;
        *(float4*)&T[r][c] = *(const float4*)(in + (size_t)(k0 + r) * 1024 + n0 + c);
    }
    __syncthreads();
    #pragma unroll
    for (int it = 0; it < 4; ++it) {
        const int s = it * 256 + t;
        const int rr = s >> 4, cc = (s & 15) * 4;   // rr: n-local, cc: k-local
        ushort4 o;
        o.x = (unsigned short)f2bs(T[cc + 0][rr]);
        o.y = (unsigned short)f2bs(T[cc + 1][rr]);
        o.z = (unsigned short)f2bs(T[cc + 2][rr]);
        o.w = (unsigned short)f2bs(T[cc + 3][rr]);
        *(ushort4*)(out + (size_t)(n0 + rr) * 1024 + k0 + cc) = o;
    }
}

// ---------------------------------------------------------------------------
// MFMA GEMM (m97 structure, verified R6/R8): C[z] = A @ BT[z]^T + bias[z]
// 128x128 tile, BK=64, 256 thr = 4 waves of 64x64.
// global_load_lds width=16 staging; XOR-swizzled unpadded LDS.
// ---------------------------------------------------------------------------
__global__ __launch_bounds__(256, 3) void gemm_bt(
    const short* __restrict__ A, const short* __restrict__ BTbase,
    const float* __restrict__ b0, const float* __restrict__ b1,
    const float* __restrict__ b2, short* __restrict__ Cbase)
{
    __shared__ __align__(16) short As[128 * 64];
    __shared__ __align__(16) short Bs[128 * 64];

    const int z = blockIdx.z;
    const short* BT = BTbase + (size_t)z * 1024 * 1024;
    const float* bias = (z == 0) ? b0 : (z == 1) ? b1 : b2;
    short* C = Cbase + (size_t)z * BS * Dc;

    const int t = threadIdx.x;
    const int lane = t & 63, w = t >> 6;
    const int quad = lane >> 4, l16 = lane & 15;
    const int wm = (w & 1) * 64, wn = (w >> 1) * 64;
    const int row0 = blockIdx.y * 128;
    const int col0 = blockIdx.x * 128;
    const int sw = l16 & 7;   // fragment-read swizzle key (row & 7)

    f32x4 acc[4][4] = {};

    for (int kt = 0; kt < 1024; kt += 64) {
        __syncthreads();
        #pragma unroll
        for (int i = 0; i < 4; ++i) {
            const int f = i * 256 + t;            // 16B slot index 0..1023
            const int r = f >> 3;                 // tile row 0..127
            const int g = (f & 7) ^ (r & 7);      // swizzled global seg
            short* lb = &As[(i * 256 + w * 64) * 8];   // wave-uniform base
            gl_lds16(A + (size_t)(row0 + r) * 1024 + kt + g * 8, lb);
            short* lb2 = &Bs[(i * 256 + w * 64) * 8];
            gl_lds16(BT + (size_t)(col0 + r) * 1024 + kt + g * 8, lb2);
        }
        __syncthreads();   // drains vmcnt before use
        #pragma unroll
        for (int ks = 0; ks < 2; ++ks) {
            bf16x8 av[4], bv[4];
            #pragma unroll
            for (int mt = 0; mt < 4; ++mt) {
                const int r = wm + mt * 16 + l16;
                av[mt] = *(const bf16x8*)&As[r * 64 + ((ks * 4 + quad) ^ sw) * 8];
            }
            #pragma unroll
            for (int nt = 0; nt < 4; ++nt) {
                const int r = wn + nt * 16 + l16;
                bv[nt] = *(const bf16x8*)&Bs[r * 64 + ((ks * 4 + quad) ^ sw) * 8];
            }
            #pragma unroll
            for (int mt = 0; mt < 4; ++mt)
                #pragma unroll
                for (int nt = 0; nt < 4; ++nt)
                    acc[mt][nt] = __builtin_amdgcn_mfma_f32_16x16x32_bf16(
                        av[mt], bv[nt], acc[mt][nt], 0, 0, 0);
        }
    }

    float bvv[4];
    #pragma unroll
    for (int nt = 0; nt < 4; ++nt) bvv[nt] = bias[col0 + wn + nt * 16 + l16];
    #pragma unroll
    for (int mt = 0; mt < 4; ++mt)
        #pragma unroll
        for (int reg = 0; reg < 4; ++reg) {
            const size_t row = row0 + wm + mt * 16 + quad * 4 + reg;
            #pragma unroll
            for (int nt = 0; nt < 4; ++nt) {
                const int col = col0 + wn + nt * 16 + l16;
                C[row * 1024 + col] = f2bs(acc[mt][nt][reg] + bvv[nt]);
            }
        }
}

// ---------------------------------------------------------------------------
// softmax(step) + PV for one 16-row q-fragment vs the staged 64-key tile.
// No online max (scores O(1)): p=exp(s), masked s=-87. l accumulates raw.
// Layouts (HW-validated R3-R8): A-frag A[m=l16][k=quad*8+j]; B-frag
// B[k=quad*8+j][n=l16]; C/D row=quad*4+reg, col=l16.
// ---------------------------------------------------------------------------
__device__ __forceinline__ void qtile_step(
    const bf16x8 (&qf)[2], const bf16x8 (&kf)[2][4],
    const short (&VsT)[64][72], short (&Psw)[16][72],
    const int k0, const int row_base,
    const int quad, const int l16,
    float (&l)[4], f32x4 (&O)[4])
{
    f32x4 S[4] = {};
    #pragma unroll
    for (int ks = 0; ks < 2; ++ks)
        #pragma unroll
        for (int nt = 0; nt < 4; ++nt)
            S[nt] = __builtin_amdgcn_mfma_f32_16x16x32_bf16(qf[ks], kf[ks][nt], S[nt], 0, 0, 0);

    #pragma unroll
    for (int nt = 0; nt < 4; ++nt) {
        const int col = k0 + nt * 16 + l16;
        #pragma unroll
        for (int reg = 0; reg < 4; ++reg) {
            const int row = row_base + quad * 4 + reg;
            const float s = (col > row) ? fminf(S[nt][reg] * 0.125f, 80.f) : -87.0f;
            const float p = __expf(s);
            S[nt][reg] = p;
            l[reg] += p;
        }
    }

    // publish P (C-layout -> A-layout via wave-local LDS)
    #pragma unroll
    for (int nt = 0; nt < 4; ++nt)
        #pragma unroll
        for (int reg = 0; reg < 4; ++reg)
            Psw[quad * 4 + reg][nt * 16 + l16] = f2bs(S[nt][reg]);

    #pragma unroll
    for (int ks = 0; ks < 2; ++ks) {
        const bf16x8 pf = *(const bf16x8*)&Psw[l16][ks * 32 + quad * 8];
        #pragma unroll
        for (int nt = 0; nt < 4; ++nt) {
            const bf16x8 vf = *(const bf16x8*)&VsT[nt * 16 + l16][ks * 32 + quad * 8];
            O[nt] = __builtin_amdgcn_mfma_f32_16x16x32_bf16(pf, vf, O[nt], 0, 0, 0);
        }
    }
}

// ---------------------------------------------------------------------------
// Split-K MFMA flash attention (strict-upper mask, attend j > i).
// Grid (64,16,2): blockIdx.x = qs*2 + half. q-tile qs needs key tiles
// [qs,32) = n tiles; half0 walks the first ceil(n/2), half1 the rest ->
// MAX 16 serial tile-steps per block (R8 post-mortem: time scales with the
// longest per-block serial step chain, 32 until now).
// Partial (O,l) are plain sums (no max rescale) written to DISJOINT
// per-half buffers (bf16 O + f32 l) -- no atomics, no memset (R6 autopsy:
// the HBM atomic RMW was the regression, not split-K). Empty range
// (qs=31,half1) writes zeros. combine() adds+normalizes in-place.
// ---------------------------------------------------------------------------
__global__ __launch_bounds__(256, 4) void attn_split(
    const short* __restrict__ Qg, const short* __restrict__ Kg,
    const short* __restrict__ Vg,
    short* __restrict__ Pa, short* __restrict__ Pb,
    float* __restrict__ l0, float* __restrict__ l1)
{
    __shared__ __align__(16) short Ks [64][72];      // [key][d]
    __shared__ __align__(16) short VsT[64][72];      // [d][key]
    __shared__ __align__(16) short Ps[4][16][72];    // per-wave [m][key]

    const int tid  = threadIdx.x;
    const int lane = tid & 63, w = tid >> 6;
    const int quad = lane >> 4, l16 = lane & 15;
    const int qs   = blockIdx.x >> 1;
    const int half = blockIdx.x & 1;
    const int h  = blockIdx.y;
    const int b  = blockIdx.z;
    const size_t rb = (size_t)b * Sc;
    const int cb = h * DHc;

    const int q0 = qs * 64;
    const int n  = NT - qs;
    const int h0 = (n + 1) >> 1;
    const int t_begin = half ? (qs + h0) : qs;
    const int t_end   = half ? NT : (qs + h0);
    short* Pout = half ? Pb : Pa;
    float* lout = half ? l1 : l0;

    // Q fragment for this wave's 16 rows
    bf16x8 qf[2];
    {
        const short* qp = Qg + (rb + q0 + w * 16 + l16) * (size_t)Dc + cb + quad * 8;
        qf[0] = *(const bf16x8*)(qp);
        qf[1] = *(const bf16x8*)(qp + 32);
    }

    float l[4] = {};
    f32x4 O[4] = {};

    // staging: thread stages 16 d of one key row (32B K + 32B V)
    const int skey = tid & 63, sseg = (tid >> 6) * 16;

    if (t_begin < t_end) {
        {   // stage first tile
            const size_t g = (rb + t_begin * 64 + skey) * (size_t)Dc + cb + sseg;
            const bf16x8 k0v = *(const bf16x8*)(Kg + g);
            const bf16x8 k1v = *(const bf16x8*)(Kg + g + 8);
            const bf16x8 v0v = *(const bf16x8*)(Vg + g);
            const bf16x8 v1v = *(const bf16x8*)(Vg + g + 8);
            *(bf16x8*)&Ks[skey][sseg]     = k0v;
            *(bf16x8*)&Ks[skey][sseg + 8] = k1v;
            #pragma unroll
            for (int e = 0; e < 8; ++e) {
                VsT[sseg + e][skey]     = v0v[e];
                VsT[sseg + 8 + e][skey] = v1v[e];
            }
        }
        __syncthreads();

        for (int t = t_begin; t < t_end; ++t) {
            const bool havenext = (t + 1 < t_end);
            bf16x8 pk0, pk1, pv0, pv1;
            if (havenext) {   // register prefetch of tile t+1
                const size_t g = (rb + (t + 1) * 64 + skey) * (size_t)Dc + cb + sseg;
                pk0 = *(const bf16x8*)(Kg + g);
                pk1 = *(const bf16x8*)(Kg + g + 8);
                pv0 = *(const bf16x8*)(Vg + g);
                pv1 = *(const bf16x8*)(Vg + g + 8);
            }

            bf16x8 kf[2][4];
            #pragma unroll
            for (int ks = 0; ks < 2; ++ks)
                #pragma unroll
                for (int nt = 0; nt < 4; ++nt)
                    kf[ks][nt] = *(const bf16x8*)&Ks[nt * 16 + l16][ks * 32 + quad * 8];

            qtile_step(qf, kf, VsT, Ps[w], t * 64, q0 + w * 16, quad, l16, l, O);

            if (havenext) {
                __syncthreads();
                *(bf16x8*)&Ks[skey][sseg]     = pk0;
                *(bf16x8*)&Ks[skey][sseg + 8] = pk1;
                #pragma unroll
                for (int e = 0; e < 8; ++e) {
                    VsT[sseg + e][skey]     = pv0[e];
                    VsT[sseg + 8 + e][skey] = pv1[e];
                }
                __syncthreads();
            }
        }
    }

    // reduce l across the 16 column-lanes, then store partials (plain writes)
    #pragma unroll
    for (int off = 1; off < 16; off <<= 1)
        #pragma unroll
        for (int reg = 0; reg < 4; ++reg)
            l[reg] += __shfl_xor(l[reg], off, 64);

    #pragma unroll
    for (int nt = 0; nt < 4; ++nt)
        #pragma unroll
        for (int reg = 0; reg < 4; ++reg) {
            const size_t row = rb + q0 + w * 16 + quad * 4 + reg;
            Pout[row * Dc + cb + nt * 16 + l16] = f2bs(O[nt][reg]);
        }
    if (l16 == 0)
        #pragma unroll
        for (int reg = 0; reg < 4; ++reg)
            lout[(rb + q0 + w * 16 + quad * 4 + reg) * Hc + h] = l[reg];
}

// ---------------------------------------------------------------------------
// In-place combine: Pa = bf16( (Pa + Pb) / (l0 + l1) ). One block per row.
// Per-element, no races. Row S-1 yields finite junk (l ~ 1e-36, normal f32);
// vmean overwrites it afterwards.
// ---------------------------------------------------------------------------
__global__ __launch_bounds__(256) void combine(
    short* __restrict__ Pa, const short* __restrict__ Pb,
    const float* __restrict__ l0, const float* __restrict__ l1)
{
    const int r = blockIdx.x;
    const int t = threadIdx.x;
    const int c = t * 4;
    const int h = t >> 4;   // c>>6
    const float rl = 1.0f / (l0[(size_t)r * Hc + h] + l1[(size_t)r * Hc + h]);
    const ushort4 a = *(const ushort4*)(Pa + (size_t)r * Dc + c);
    const ushort4 bv = *(const ushort4*)(Pb + (size_t)r * Dc + c);
    ushort4 o;
    o.x = (unsigned short)f2bs((bs2f(a.x) + bs2f(bv.x)) * rl);
    o.y = (unsigned short)f2bs((bs2f(a.y) + bs2f(bv.y)) * rl);
    o.z = (unsigned short)f2bs((bs2f(a.z) + bs2f(bv.z)) * rl);
    o.w = (unsigned short)f2bs((bs2f(a.w) + bs2f(bv.w)) * rl);
    *(ushort4*)(Pa + (size_t)r * Dc + c) = o;
}

// ---------------------------------------------------------------------------
// Row S-1 fully masked: reference softmax of all-(-1e9) is exactly uniform
// 1/S -> ctx = mean_j V[b,j,h,:]. Overwrites combine's placeholder.
// ---------------------------------------------------------------------------
__global__ __launch_bounds__(256) void vmean(const short* __restrict__ V,
                                             short* __restrict__ CTX)
{
    const int h = blockIdx.x, b = blockIdx.y;
    const int t = threadIdx.x;
    const int dh = t & 63, ck = t >> 6;      // 4 chunks of 512 keys
    float s = 0.f;
    const short* vp = V + ((size_t)b * Sc + ck * 512) * Dc + h * DHc + dh;
    for (int j = 0; j < 512; ++j) s += bs2f(vp[(size_t)j * Dc]);
    __shared__ float red[4][64];
    red[ck][dh] = s;
    __syncthreads();
    if (ck == 0) {
        const float tot = (red[0][dh] + red[1][dh] + red[2][dh] + red[3][dh]) * (1.f / Sc);
        CTX[((size_t)b * Sc + Sc - 1) * Dc + h * DHc + dh] = f2bs(tot);
    }
}

// ---------------------------------------------------------------------------
// out = LayerNorm(x + attn_out) * gamma + beta; x f32, AO bf16, out f32
// ---------------------------------------------------------------------------
__global__ __launch_bounds__(256, 4) void resid_ln(
    const float* __restrict__ X, const short* __restrict__ AO,
    const float* __restrict__ gamma, const float* __restrict__ beta,
    float* __restrict__ out)
{
    const int r = blockIdx.x;
    const int t = threadIdx.x;
    const size_t base = (size_t)r * Dc + t * 4;

    const float4 x4 = *(const float4*)(X + base);
    const ushort4 a4 = *(const ushort4*)(AO + base);
    float y[4];
    y[0] = x4.x + bs2f(a4.x);
    y[1] = x4.y + bs2f(a4.y);
    y[2] = x4.z + bs2f(a4.z);
    y[3] = x4.w + bs2f(a4.w);

    float s  = y[0] + y[1] + y[2] + y[3];
    float s2 = y[0]*y[0] + y[1]*y[1] + y[2]*y[2] + y[3]*y[3];
    #pragma unroll
    for (int off = 1; off < 64; off <<= 1) {
        s  += __shfl_xor(s,  off, 64);
        s2 += __shfl_xor(s2, off, 64);
    }
    __shared__ float red[8];
    const int w = t >> 6;
    if ((t & 63) == 0) { red[w] = s; red[4 + w] = s2; }
    __syncthreads();
    s  = red[0] + red[1] + red[2] + red[3];
    s2 = red[4] + red[5] + red[6] + red[7];

    const float mu   = s * (1.0f / Dc);
    const float rstd = rsqrtf(s2 * (1.0f / Dc) - mu * mu + 1e-6f);

    const float4 g4 = *(const float4*)(gamma + t * 4);
    const float4 b4 = *(const float4*)(beta  + t * 4);
    float4 o;
    o.x = (y[0] - mu) * rstd * g4.x + b4.x;
    o.y = (y[1] - mu) * rstd * g4.y + b4.y;
    o.z = (y[2] - mu) * rstd * g4.z + b4.z;
    o.w = (y[3] - mu) * rstd * g4.w + b4.w;
    *(float4*)(out + base) = o;
}

// ---------------------------------------------------------------------------
extern "C" void kernel_launch(void* const* d_in, const int* in_sizes, int n_in,
                              void* d_out, int out_size, void* d_ws, size_t ws_size,
                              hipStream_t stream)
{
    (void)in_sizes; (void)n_in; (void)out_size; (void)ws_size;
    const float* x     = (const float*)d_in[0];
    const float* Wq    = (const float*)d_in[1];
    const float* bq    = (const float*)d_in[2];
    const float* Wk    = (const float*)d_in[3];
    const float* bk    = (const float*)d_in[4];
    const float* Wv    = (const float*)d_in[5];
    const float* bv    = (const float*)d_in[6];
    const float* Wo    = (const float*)d_in[7];
    const float* bo    = (const float*)d_in[8];
    const float* gamma = (const float*)d_in[9];
    const float* beta  = (const float*)d_in[10];
    float* out = (float*)d_out;

    const size_t matN = (size_t)BS * Dc;       // 4,194,304
    const size_t wN   = (size_t)Dc * Dc;       // 1,048,576
    // ws: 48.5 MB (same as R7/R8 + l-bufs). Pb overlays xb (dead after QKV
    // gemm); combined ctx lives in Pa; AO overlays Qb (dead after attn).
    short* xb = (short*)d_ws;                  // 8 MB
    short* WT = xb + matN;                     // 8 MB (4 transposed weights)
    short* Qb = WT + 4 * wN;                   // 8 MB
    short* Kb = Qb + matN;                     // 8 MB
    short* Vb = Kb + matN;                     // 8 MB
    short* Pa = Vb + matN;                     // 8 MB (half0 partial -> ctx)
    short* Pb = xb;                            //      (half1 partial, xb dead)
    float* l0 = (float*)(Pa + matN);           // 256 KB
    float* l1 = l0 + (size_t)BS * Hc;          // 256 KB
    short* AO = Qb;                            // Q dead after attention

    cast_x<<<matN / 1024, 256, 0, stream>>>(x, xb);

    dim3 gt(16, 16, 4);
    transpose_cast<<<gt, 256, 0, stream>>>(Wq, Wk, Wv, Wo, WT);

    dim3 gq(Dc / 128, BS / 128, 3);            // (8, 32, 3)
    gemm_bt<<<gq, 256, 0, stream>>>(xb, WT, bq, bk, bv, Qb);

    dim3 ga(2 * NT, Hc, Bc);                   // (64, 16, 2): qs*2 + half
    attn_split<<<ga, 256, 0, stream>>>(Qb, Kb, Vb, Pa, Pb, l0, l1);

    combine<<<BS, 256, 0, stream>>>(Pa, Pb, l0, l1);

    dim3 gv(Hc, Bc);
    vmean<<<gv, 256, 0, stream>>>(Vb, Pa);     // fix up row S-1 (uniform softmax)

    dim3 go(Dc / 128, BS / 128, 1);
    gemm_bt<<<go, 256, 0, stream>>>(Pa, WT + 3 * wN, bo, bo, bo, AO);

    resid_ln<<<BS, 256, 0, stream>>>(x, AO, gamma, beta, out);
}

// Round 10
// 239.312 us; speedup vs baseline: 1.0415x; 1.0415x over previous
//
#include <hip/hip_runtime.h>
#include <hip/hip_bf16.h>

typedef __hip_bfloat16 bf16;
typedef __attribute__((ext_vector_type(8))) short bf16x8;   // 8 bf16 = 4 VGPRs
typedef __attribute__((ext_vector_type(4))) float f32x4;

constexpr int Bc  = 2;
constexpr int Sc  = 2048;
constexpr int Dc  = 1024;
constexpr int Hc  = 16;
constexpr int DHc = 64;
constexpr int BS  = Bc * Sc;   // 4096 rows
constexpr int NT  = Sc / 64;   // 32 key tiles

__device__ __forceinline__ float bs2f(unsigned short u) {
    union { unsigned int i; float f; } v; v.i = ((unsigned int)u) << 16; return v.f;
}
__device__ __forceinline__ short f2bs(float x) {
    bf16 h = __float2bfloat16(x);
    return *reinterpret_cast<short*>(&h);
}

// async global->LDS, 16B per lane. LDS dest is wave-uniform base + lane*16.
typedef const __attribute__((address_space(1))) unsigned int* as1_u32p;
typedef __attribute__((address_space(3))) unsigned int* as3_u32p;
__device__ __forceinline__ void gl_lds16(const void* g, void* l) {
    __builtin_amdgcn_global_load_lds((as1_u32p)g, (as3_u32p)l, 16, 0, 0);
}

// ---------------------------------------------------------------------------
// cast x (f32) -> bf16, same layout
// ---------------------------------------------------------------------------
__global__ __launch_bounds__(256) void cast_x(const float* __restrict__ in,
                                              short* __restrict__ out) {
    const int i = (blockIdx.x * 256 + threadIdx.x) * 4;
    const float4 v = *(const float4*)(in + i);
    ushort4 o;
    o.x = (unsigned short)f2bs(v.x);
    o.y = (unsigned short)f2bs(v.y);
    o.z = (unsigned short)f2bs(v.z);
    o.w = (unsigned short)f2bs(v.w);
    *(ushort4*)(out + i) = o;
}

// ---------------------------------------------------------------------------
// transpose + cast: in f32 [1024 k][1024 n] -> out bf16 [n][k].  z picks W.
// ---------------------------------------------------------------------------
__global__ __launch_bounds__(256) void transpose_cast(
    const float* __restrict__ w0, const float* __restrict__ w1,
    const float* __restrict__ w2, const float* __restrict__ w3,
    short* __restrict__ outbase)
{
    __shared__ float T[64][65];
    const int z = blockIdx.z;
    const float* in = (z == 0) ? w0 : (z == 1) ? w1 : (z == 2) ? w2 : w3;
    short* out = outbase + (size_t)z * 1024 * 1024;
    const int k0 = blockIdx.x * 64, n0 = blockIdx.y * 64;
    const int t = threadIdx.x;
    #pragma unroll
    for (int it = 0; it < 4; ++it) {
        const int s = it * 256 + t;
        const int r = s >> 4, c = (s & 15) * 4;
        *(float4*)&T[r][c] = *(const float4*)(in + (size_t)(k0 + r) * 1024 + n0 + c);
    }
    __syncthreads();
    #pragma unroll
    for (int it = 0; it < 4; ++it) {
        const int s = it * 256 + t;
        const int rr = s >> 4, cc = (s & 15) * 4;   // rr: n-local, cc: k-local
        ushort4 o;
        o.x = (unsigned short)f2bs(T[cc + 0][rr]);
        o.y = (unsigned short)f2bs(T[cc + 1][rr]);
        o.z = (unsigned short)f2bs(T[cc + 2][rr]);
        o.w = (unsigned short)f2bs(T[cc + 3][rr]);
        *(ushort4*)(out + (size_t)(n0 + rr) * 1024 + k0 + cc) = o;
    }
}

// ---------------------------------------------------------------------------
// MFMA GEMM (m97 structure, verified R6-R9): C[z] = A @ BT[z]^T + bias[z].
// qsc: output scale applied to z==0 only (folds softmax 1/8 into Q; exact,
// power of 2). 128x128 tile, BK=64, global_load_lds + XOR-swizzled LDS.
// ---------------------------------------------------------------------------
__global__ __launch_bounds__(256, 3) void gemm_bt(
    const short* __restrict__ A, const short* __restrict__ BTbase,
    const float* __restrict__ b0, const float* __restrict__ b1,
    const float* __restrict__ b2, short* __restrict__ Cbase,
    const float qsc)
{
    __shared__ __align__(16) short As[128 * 64];
    __shared__ __align__(16) short Bs[128 * 64];

    const int z = blockIdx.z;
    const short* BT = BTbase + (size_t)z * 1024 * 1024;
    const float* bias = (z == 0) ? b0 : (z == 1) ? b1 : b2;
    const float osc = (z == 0) ? qsc : 1.0f;
    short* C = Cbase + (size_t)z * BS * Dc;

    const int t = threadIdx.x;
    const int lane = t & 63, w = t >> 6;
    const int quad = lane >> 4, l16 = lane & 15;
    const int wm = (w & 1) * 64, wn = (w >> 1) * 64;
    const int row0 = blockIdx.y * 128;
    const int col0 = blockIdx.x * 128;
    const int sw = l16 & 7;   // fragment-read swizzle key (row & 7)

    f32x4 acc[4][4] = {};

    for (int kt = 0; kt < 1024; kt += 64) {
        __syncthreads();
        #pragma unroll
        for (int i = 0; i < 4; ++i) {
            const int f = i * 256 + t;            // 16B slot index 0..1023
            const int r = f >> 3;                 // tile row 0..127
            const int g = (f & 7) ^ (r & 7);      // swizzled global seg
            short* lb = &As[(i * 256 + w * 64) * 8];   // wave-uniform base
            gl_lds16(A + (size_t)(row0 + r) * 1024 + kt + g * 8, lb);
            short* lb2 = &Bs[(i * 256 + w * 64) * 8];
            gl_lds16(BT + (size_t)(col0 + r) * 1024 + kt + g * 8, lb2);
        }
        __syncthreads();   // drains vmcnt before use
        #pragma unroll
        for (int ks = 0; ks < 2; ++ks) {
            bf16x8 av[4], bv[4];
            #pragma unroll
            for (int mt = 0; mt < 4; ++mt) {
                const int r = wm + mt * 16 + l16;
                av[mt] = *(const bf16x8*)&As[r * 64 + ((ks * 4 + quad) ^ sw) * 8];
            }
            #pragma unroll
            for (int nt = 0; nt < 4; ++nt) {
                const int r = wn + nt * 16 + l16;
                bv[nt] = *(const bf16x8*)&Bs[r * 64 + ((ks * 4 + quad) ^ sw) * 8];
            }
            #pragma unroll
            for (int mt = 0; mt < 4; ++mt)
                #pragma unroll
                for (int nt = 0; nt < 4; ++nt)
                    acc[mt][nt] = __builtin_amdgcn_mfma_f32_16x16x32_bf16(
                        av[mt], bv[nt], acc[mt][nt], 0, 0, 0);
        }
    }

    float bvv[4];
    #pragma unroll
    for (int nt = 0; nt < 4; ++nt) bvv[nt] = bias[col0 + wn + nt * 16 + l16];
    #pragma unroll
    for (int mt = 0; mt < 4; ++mt)
        #pragma unroll
        for (int reg = 0; reg < 4; ++reg) {
            const size_t row = row0 + wm + mt * 16 + quad * 4 + reg;
            #pragma unroll
            for (int nt = 0; nt < 4; ++nt) {
                const int col = col0 + wn + nt * 16 + l16;
                C[row * 1024 + col] = f2bs((acc[mt][nt][reg] + bvv[nt]) * osc);
            }
        }
}

// ---------------------------------------------------------------------------
// MFMA flash attention, strict-upper mask (attend j > i), 32 q-rows/wave.
// R8/R9 post-mortem: kernel is LDS-pipe bound (74% busy), not chain-bound.
// Fix: each wave owns 32 rows (2 mt of 16) so kf/vf fragment reads are
// amortized over 2x rows: 20 b128/step vs 36 for two 16-row steps (-44%).
// Block = 4 waves = 128-row q-block qb, sweeping tiles [2qb, 32).
// Grid (16,16,2) = 2 blocks/CU; qb = x ^ (z?15:0) pairs chains (32-2x) and
// (2+2x) on co-scheduled blocks n, n+256 (round-robin heuristic; perf only).
// Masked p = exact 0 (matches reference: exp(-1e9) underflows to 0 in f32).
// Q pre-scaled by 0.125 in gemm. Row S-1 (l=0 -> NaN) overwritten by vmean.
// Layouts (HW-validated R3-R9): A[m=l16][k=quad*8+j]; B[k=quad*8+j][n=l16];
// C/D row=quad*4+reg, col=l16.
// ---------------------------------------------------------------------------
__global__ __launch_bounds__(256, 2) void attn_mfma(
    const short* __restrict__ Qg, const short* __restrict__ Kg,
    const short* __restrict__ Vg, short* __restrict__ CTX)
{
    __shared__ __align__(16) short Ks [64][72];      // [key][d]
    __shared__ __align__(16) short VsT[64][72];      // [d][key]
    __shared__ __align__(16) short Ps[4][32][72];    // per-wave [m 0..31][key]

    const int tid  = threadIdx.x;
    const int lane = tid & 63, w = tid >> 6;
    const int quad = lane >> 4, l16 = lane & 15;
    const int qb = blockIdx.x ^ (blockIdx.z ? 15 : 0);   // CU-pair balance swizzle
    const int h  = blockIdx.y;
    const int b  = blockIdx.z;
    const size_t rb = (size_t)b * Sc;
    const int cb = h * DHc;

    const int q0 = qb * 128 + w * 32;    // this wave's 32 q-rows
    const int t0 = qb * 2;               // first key tile with any allowed key

    // Q fragments (pre-scaled by 0.125 in gemm): qf[mt][ks]
    bf16x8 qf[2][2];
    #pragma unroll
    for (int mt = 0; mt < 2; ++mt) {
        const short* qp = Qg + (rb + q0 + mt * 16 + l16) * (size_t)Dc + cb + quad * 8;
        qf[mt][0] = *(const bf16x8*)(qp);
        qf[mt][1] = *(const bf16x8*)(qp + 32);
    }

    float l[2][4] = {};
    f32x4 O[2][4] = {};

    // staging: thread stages 16 d of one key row (32B K + 32B V)
    const int skey = tid & 63, sseg = (tid >> 6) * 16;

    {   // stage first tile
        const size_t g = (rb + t0 * 64 + skey) * (size_t)Dc + cb + sseg;
        const bf16x8 k0v = *(const bf16x8*)(Kg + g);
        const bf16x8 k1v = *(const bf16x8*)(Kg + g + 8);
        const bf16x8 v0v = *(const bf16x8*)(Vg + g);
        const bf16x8 v1v = *(const bf16x8*)(Vg + g + 8);
        *(bf16x8*)&Ks[skey][sseg]     = k0v;
        *(bf16x8*)&Ks[skey][sseg + 8] = k1v;
        #pragma unroll
        for (int e = 0; e < 8; ++e) {
            VsT[sseg + e][skey]     = v0v[e];
            VsT[sseg + 8 + e][skey] = v1v[e];
        }
    }
    __syncthreads();

    for (int t = t0; t < NT; ++t) {
        const bool havenext = (t + 1 < NT);
        bf16x8 pk0, pk1, pv0, pv1;
        if (havenext) {   // register prefetch of tile t+1 (drains at barrier)
            const size_t g = (rb + (t + 1) * 64 + skey) * (size_t)Dc + cb + sseg;
            pk0 = *(const bf16x8*)(Kg + g);
            pk1 = *(const bf16x8*)(Kg + g + 8);
            pv0 = *(const bf16x8*)(Vg + g);
            pv1 = *(const bf16x8*)(Vg + g + 8);
        }

        // --- QK for both row-halves, kf read ONCE ---
        bf16x8 kf[2][4];
        #pragma unroll
        for (int ks = 0; ks < 2; ++ks)
            #pragma unroll
            for (int nt = 0; nt < 4; ++nt)
                kf[ks][nt] = *(const bf16x8*)&Ks[nt * 16 + l16][ks * 32 + quad * 8];

        f32x4 S[2][4] = {};
        #pragma unroll
        for (int ks = 0; ks < 2; ++ks)
            #pragma unroll
            for (int nt = 0; nt < 4; ++nt) {
                S[0][nt] = __builtin_amdgcn_mfma_f32_16x16x32_bf16(qf[0][ks], kf[ks][nt], S[0][nt], 0, 0, 0);
                S[1][nt] = __builtin_amdgcn_mfma_f32_16x16x32_bf16(qf[1][ks], kf[ks][nt], S[1][nt], 0, 0, 0);
            }

        // --- softmax terms + publish P (exact 0 where masked) ---
        #pragma unroll
        for (int mt = 0; mt < 2; ++mt)
            #pragma unroll
            for (int nt = 0; nt < 4; ++nt) {
                const int col = t * 64 + nt * 16 + l16;
                #pragma unroll
                for (int reg = 0; reg < 4; ++reg) {
                    const int row = q0 + mt * 16 + quad * 4 + reg;
                    const float p = (col > row)
                        ? __expf(fminf(S[mt][nt][reg], 80.f)) : 0.f;
                    l[mt][reg] += p;
                    Ps[w][mt * 16 + quad * 4 + reg][nt * 16 + l16] = f2bs(p);
                }
            }

        // --- PV for both row-halves, vf read ONCE ---
        bf16x8 vf[2][4];
        #pragma unroll
        for (int ks = 0; ks < 2; ++ks)
            #pragma unroll
            for (int nt = 0; nt < 4; ++nt)
                vf[ks][nt] = *(const bf16x8*)&VsT[nt * 16 + l16][ks * 32 + quad * 8];
        #pragma unroll
        for (int mt = 0; mt < 2; ++mt)
            #pragma unroll
            for (int ks = 0; ks < 2; ++ks) {
                const bf16x8 pf = *(const bf16x8*)&Ps[w][mt * 16 + l16][ks * 32 + quad * 8];
                #pragma unroll
                for (int nt = 0; nt < 4; ++nt)
                    O[mt][nt] = __builtin_amdgcn_mfma_f32_16x16x32_bf16(pf, vf[ks][nt], O[mt][nt], 0, 0, 0);
            }

        if (havenext) {
            __syncthreads();
            *(bf16x8*)&Ks[skey][sseg]     = pk0;
            *(bf16x8*)&Ks[skey][sseg + 8] = pk1;
            #pragma unroll
            for (int e = 0; e < 8; ++e) {
                VsT[sseg + e][skey]     = pv0[e];
                VsT[sseg + 8 + e][skey] = pv1[e];
            }
            __syncthreads();
        }
    }

    // deferred 16-lane reduction of l, normalize, store
    #pragma unroll
    for (int off = 1; off < 16; off <<= 1)
        #pragma unroll
        for (int mt = 0; mt < 2; ++mt)
            #pragma unroll
            for (int reg = 0; reg < 4; ++reg)
                l[mt][reg] += __shfl_xor(l[mt][reg], off, 64);
    #pragma unroll
    for (int mt = 0; mt < 2; ++mt)
        #pragma unroll
        for (int reg = 0; reg < 4; ++reg)
            l[mt][reg] = 1.0f / l[mt][reg];
    #pragma unroll
    for (int mt = 0; mt < 2; ++mt)
        #pragma unroll
        for (int nt = 0; nt < 4; ++nt)
            #pragma unroll
            for (int reg = 0; reg < 4; ++reg) {
                const size_t row = rb + q0 + mt * 16 + quad * 4 + reg;
                CTX[row * Dc + cb + nt * 16 + l16] = f2bs(O[mt][nt][reg] * l[mt][reg]);
            }
}

// ---------------------------------------------------------------------------
// Row S-1 fully masked: reference softmax of all-(-1e9) is exactly uniform
// 1/S -> ctx = mean_j V[b,j,h,:]. Overwrites attn's NaN placeholder.
// ---------------------------------------------------------------------------
__global__ __launch_bounds__(256) void vmean(const short* __restrict__ V,
                                             short* __restrict__ CTX)
{
    const int h = blockIdx.x, b = blockIdx.y;
    const int t = threadIdx.x;
    const int dh = t & 63, ck = t >> 6;      // 4 chunks of 512 keys
    float s = 0.f;
    const short* vp = V + ((size_t)b * Sc + ck * 512) * Dc + h * DHc + dh;
    for (int j = 0; j < 512; ++j) s += bs2f(vp[(size_t)j * Dc]);
    __shared__ float red[4][64];
    red[ck][dh] = s;
    __syncthreads();
    if (ck == 0) {
        const float tot = (red[0][dh] + red[1][dh] + red[2][dh] + red[3][dh]) * (1.f / Sc);
        CTX[((size_t)b * Sc + Sc - 1) * Dc + h * DHc + dh] = f2bs(tot);
    }
}

// ---------------------------------------------------------------------------
// out = LayerNorm(x + attn_out) * gamma + beta; x f32, AO bf16, out f32
// ---------------------------------------------------------------------------
__global__ __launch_bounds__(256, 4) void resid_ln(
    const float* __restrict__ X, const short* __restrict__ AO,
    const float* __restrict__ gamma, const float* __restrict__ beta,
    float* __restrict__ out)
{
    const int r = blockIdx.x;
    const int t = threadIdx.x;
    const size_t base = (size_t)r * Dc + t * 4;

    const float4 x4 = *(const float4*)(X + base);
    const ushort4 a4 = *(const ushort4*)(AO + base);
    float y[4];
    y[0] = x4.x + bs2f(a4.x);
    y[1] = x4.y + bs2f(a4.y);
    y[2] = x4.z + bs2f(a4.z);
    y[3] = x4.w + bs2f(a4.w);

    float s  = y[0] + y[1] + y[2] + y[3];
    float s2 = y[0]*y[0] + y[1]*y[1] + y[2]*y[2] + y[3]*y[3];
    #pragma unroll
    for (int off = 1; off < 64; off <<= 1) {
        s  += __shfl_xor(s,  off, 64);
        s2 += __shfl_xor(s2, off, 64);
    }
    __shared__ float red[8];
    const int w = t >> 6;
    if ((t & 63) == 0) { red[w] = s; red[4 + w] = s2; }
    __syncthreads();
    s  = red[0] + red[1] + red[2] + red[3];
    s2 = red[4] + red[5] + red[6] + red[7];

    const float mu   = s * (1.0f / Dc);
    const float rstd = rsqrtf(s2 * (1.0f / Dc) - mu * mu + 1e-6f);

    const float4 g4 = *(const float4*)(gamma + t * 4);
    const float4 b4 = *(const float4*)(beta  + t * 4);
    float4 o;
    o.x = (y[0] - mu) * rstd * g4.x + b4.x;
    o.y = (y[1] - mu) * rstd * g4.y + b4.y;
    o.z = (y[2] - mu) * rstd * g4.z + b4.z;
    o.w = (y[3] - mu) * rstd * g4.w + b4.w;
    *(float4*)(out + base) = o;
}

// ---------------------------------------------------------------------------
extern "C" void kernel_launch(void* const* d_in, const int* in_sizes, int n_in,
                              void* d_out, int out_size, void* d_ws, size_t ws_size,
                              hipStream_t stream)
{
    (void)in_sizes; (void)n_in; (void)out_size; (void)ws_size;
    const float* x     = (const float*)d_in[0];
    const float* Wq    = (const float*)d_in[1];
    const float* bq    = (const float*)d_in[2];
    const float* Wk    = (const float*)d_in[3];
    const float* bk    = (const float*)d_in[4];
    const float* Wv    = (const float*)d_in[5];
    const float* bv    = (const float*)d_in[6];
    const float* Wo    = (const float*)d_in[7];
    const float* bo    = (const float*)d_in[8];
    const float* gamma = (const float*)d_in[9];
    const float* beta  = (const float*)d_in[10];
    float* out = (float*)d_out;

    const size_t matN = (size_t)BS * Dc;       // 4,194,304
    const size_t wN   = (size_t)Dc * Dc;       // 1,048,576
    short* xb = (short*)d_ws;                  // 8 MB
    short* WT = xb + matN;                     // 8 MB (4 transposed weights)
    short* Qb = WT + 4 * wN;                   // 8 MB
    short* Kb = Qb + matN;                     // 8 MB
    short* Vb = Kb + matN;                     // 8 MB
    short* Cx = Vb + matN;                     // 8 MB
    short* AO = Qb;                            // Q dead after attention

    cast_x<<<matN / 1024, 256, 0, stream>>>(x, xb);

    dim3 gt(16, 16, 4);
    transpose_cast<<<gt, 256, 0, stream>>>(Wq, Wk, Wv, Wo, WT);

    dim3 gq(Dc / 128, BS / 128, 3);            // (8, 32, 3)
    gemm_bt<<<gq, 256, 0, stream>>>(xb, WT, bq, bk, bv, Qb, 0.125f);

    dim3 ga(16, Hc, Bc);                       // (16, 16, 2): 128-row q-blocks
    attn_mfma<<<ga, 256, 0, stream>>>(Qb, Kb, Vb, Cx);

    dim3 gv(Hc, Bc);
    vmean<<<gv, 256, 0, stream>>>(Vb, Cx);     // fix up row S-1 (uniform softmax)

    dim3 go(Dc / 128, BS / 128, 1);
    gemm_bt<<<go, 256, 0, stream>>>(Cx, WT + 3 * wN, bo, bo, bo, AO, 1.0f);

    resid_ln<<<BS, 256, 0, stream>>>(x, AO, gamma, beta, out);
}